// Round 9
// baseline (191.652 us; speedup 1.0000x reference)
//
#include <hip/hip_runtime.h>
#include <hip/hip_bf16.h>
#include <math.h>

// Problem constants
#define NB    4096
#define DH    784
#define KX8   832            // fp8 row bytes: 784 padded to 13*64
#define NSR   5
#define NNEG  (NB*NSR)       // 20480
#define NTOT  (NB + NNEG)    // 24576

#define A_CONST 1.576943f
#define PEXP    1.7901216f   // 2*B_PARAM
#define EPS_C   1.0e-4f
#define ALPHA_C 0.9296875f   // BATCH_COUNT=500: beta=0.5*(1-500/800)^2=0.0703125
#define BETA_C  0.0703125f

#define NSLOT 64             // per row: 32 block-contribs x 2 wave-halves
#define SLAB  (NB * NSLOT)   // elements per stat component = 262144
#define NBLK  528            // 32 diag + 496 off-diag 128x128 tiles
#define BUFB  8192           // LDS buffer stride in BYTES (128 rows x 64 B)
#define POISON 0xAAAAAAAAu   // harness ws poison pattern (0xAA bytes)

typedef __hip_bfloat16 bf16;
typedef short bf16x8 __attribute__((ext_vector_type(8)));
typedef float f32x4  __attribute__((ext_vector_type(4)));
typedef long long2v __attribute__((ext_vector_type(2)));

// Workspace layout (bytes)
#define WS_XF8    0                      // 4096*832   = 3407872
#define WS_EBF    3407872                // 4096*32*2  = 262144
#define WS_SQX    3670016                // 4096*4     = 16384
#define WS_SQE    3686400                // 4096*4     = 16384
#define WS_STATSP 3702784                // 5*262144*4 = 5242880
#define WS_UPART  8945664                // 96*4       = 384
#define WS_CPART  8946048                // 64*4       = 256
#define WS_FLAGS  8946304                // 32*4       = 128
#define WS_DONE   8946432                // 4
#define WS_FIN    8946436                // 4

__device__ __forceinline__ void gl2lds16(const void* g, void* l) {
    __builtin_amdgcn_global_load_lds(
        (const __attribute__((address_space(1))) unsigned int*)g,
        (__attribute__((address_space(3))) unsigned int*)l,
        16, 0, 0);
}

// ONE kernel: strip prep (diag blocks) -> flag publish -> UMAP CE (blocks<96)
// -> strip wait -> R7 gram core (triple-buffer vmcnt(4) pipeline, fp8 X-gram,
// bf16 E tail, symmetric stats) -> arrival counter -> finish (blocks>=464).
// Co-residency guaranteed: launch_bounds(256,3) + 51200B LDS => 3 blocks/CU,
// capacity 768 >= 528, so producer/consumer spins cannot deadlock.
__global__ __launch_bounds__(256, 3) void mega_kernel(
    const float* __restrict__ X, const float* __restrict__ emb,
    const int* __restrict__ perm, unsigned char* __restrict__ Xf8,
    bf16* __restrict__ Ebf, float* __restrict__ sqx, float* __restrict__ sqe,
    float* __restrict__ statsp, float* __restrict__ upart,
    float* __restrict__ cpart, unsigned* __restrict__ flags,
    unsigned* __restrict__ done_cnt, unsigned* __restrict__ fin_cnt,
    float* __restrict__ out) {
    __shared__ __align__(16) unsigned char smem[51200];
    unsigned char* As = smem;                      // 24576 (aliased by finish ps2)
    unsigned char* Bs = smem + 24576;              // 24576
    float* sqxs = (float*)(smem + 49152);          // 256 f32
    float* sqes = (float*)(smem + 50176);          // 256 f32

    const int tid = threadIdx.x;
    const int b = blockIdx.x;
    const int wave = tid >> 6, lane = tid & 63;

    // counter init: CAS from the known 0xAA poison (safe: all arrivals happen
    // long after every block's entry CAS; once != POISON the CAS is a no-op)
    if (tid == 0) {
        atomicCAS(done_cnt, POISON, 0u);
        atomicCAS(fin_cnt, POISON, 0u);
    }

    // tile decode: diag tiles first (producers dispatched earliest)
    int bi, bj;
    if (b < 32) { bi = b; bj = b; }
    else { int k = b - 32; bi = 0; while (k >= 31 - bi) { k -= 31 - bi; ++bi; } bj = bi + 1 + k; }
    const int i0 = bi * 128, j0 = bj * 128;

    // ---- phase 0a: diag block b owns strip b: X->fp8 column-permuted + sqx,
    // e_to->bf16 + sqe. Column-permuted: dest dword c*16+q*4+h*2+w sources
    // src float4 c*16+h*8+q*2+w (lane fragment = contiguous 16B/quad).
    if (b < 32) {
        for (int rr = 0; rr < 32; ++rr) {
            const int row = b * 128 + wave * 32 + rr;
            const float4* xr = (const float4*)(X + (size_t)row * DH);
            int* xb = (int*)(Xf8 + (size_t)row * KX8);
            float s = 0.f;
            #pragma unroll
            for (int it = 0; it < 4; ++it) {
                const int src = lane + it * 64;
                if (src < 208) {
                    int pk = 0;
                    if (src < 196) {
                        float4 v = xr[src];
                        s += v.x * v.x + v.y * v.y + v.z * v.z + v.w * v.w;
                        int lo = __builtin_amdgcn_cvt_pk_fp8_f32(v.x, v.y, 0, false);
                        pk = __builtin_amdgcn_cvt_pk_fp8_f32(v.z, v.w, lo, true);
                    }
                    const int c = src >> 4, sc = src & 15;
                    const int h = sc >> 3, q = (sc >> 1) & 3, w = sc & 1;
                    xb[c * 16 + q * 4 + h * 2 + w] = pk;
                }
            }
            #pragma unroll
            for (int off = 32; off; off >>= 1) s += __shfl_down(s, off, 64);
            if (lane == 0) sqx[row] = s;
        }
        if (tid < 128) {
            const int row = b * 128 + tid;
            const float4* av = (const float4*)(emb + (size_t)row * 32);
            float4 t0 = av[0], t1 = av[1], t2 = av[2], t3 = av[3];
            bf16* eb = Ebf + (size_t)row * 32;
            union { bf16 h[4]; ushort4 u; } cv;
            #define ST4(dst, q) cv.h[0]=__float2bfloat16(q.x); cv.h[1]=__float2bfloat16(q.y); \
                                cv.h[2]=__float2bfloat16(q.z); cv.h[3]=__float2bfloat16(q.w); \
                                *(ushort4*)(dst) = cv.u;
            ST4(eb,      t0) ST4(eb + 4,  t1) ST4(eb + 8,  t2) ST4(eb + 12, t3)
            #undef ST4
            ushort4 z = {0, 0, 0, 0};
            *(ushort4*)(eb + 16) = z; *(ushort4*)(eb + 20) = z;
            *(ushort4*)(eb + 24) = z; *(ushort4*)(eb + 28) = z;
            sqe[row] = t0.x*t0.x + t0.y*t0.y + t0.z*t0.z + t0.w*t0.w
                     + t1.x*t1.x + t1.y*t1.y + t1.z*t1.z + t1.w*t1.w
                     + t2.x*t2.x + t2.y*t2.y + t2.z*t2.z + t2.w*t2.w
                     + t3.x*t3.x + t3.y*t3.y + t3.z*t3.z + t3.w*t3.w;
        }
        __syncthreads();                  // per-thread vmcnt(0): stores retired
        if (tid == 0) { __threadfence(); atomicExch(&flags[b], 1u); }  // release
    }

    // ---- phase 0b: UMAP CE partials, blocks 0..95 (96*256 = NTOT items)
    if (b < 96) {
        const int t = b * 256 + tid;
        float val;
        if (t < NB) {
            const float4* av = (const float4*)(emb + (size_t)t * 32);
            float4 t0 = av[0], t1 = av[1], t2 = av[2], t3 = av[3];
            float4 f0 = av[4], f1 = av[5], f2 = av[6], f3 = av[7];
            float d2 = 0.f;
            #define D2(a, b2) { float4 df = {a.x-b2.x, a.y-b2.y, a.z-b2.z, a.w-b2.w}; \
                                d2 += df.x*df.x + df.y*df.y + df.z*df.z + df.w*df.w; }
            D2(t0, f0) D2(t1, f1) D2(t2, f2) D2(t3, f3)
            #undef D2
            float d = sqrtf(d2);
            float p = 1.f / (1.f + A_CONST * powf(d, PEXP));
            val = -logf(fminf(fmaxf(p, EPS_C), 1.f));
        } else {
            const int k = t - NB;
            const int ti = k / 5;
            const int fi = perm[k] / 5;
            const float4* at = (const float4*)(emb + (size_t)ti * 32);
            const float4* bt = (const float4*)(emb + (size_t)fi * 32 + 16);
            float d2 = 0.f;
            #pragma unroll
            for (int q = 0; q < 4; ++q) {
                float4 a = at[q], b2 = bt[q];
                float4 df = {a.x-b2.x, a.y-b2.y, a.z-b2.z, a.w-b2.w};
                d2 += df.x*df.x + df.y*df.y + df.z*df.z + df.w*df.w;
            }
            float d = sqrtf(d2);
            float p = 1.f / (1.f + A_CONST * powf(d, PEXP));
            val = -logf(fminf(fmaxf(1.f - p, EPS_C), 1.f));
        }
        #pragma unroll
        for (int off = 32; off; off >>= 1) val += __shfl_down(val, off, 64);
        float* ps = (float*)(smem + 49152);        // alias, dead before gram sqxs
        if (lane == 0) ps[wave] = val;
        __syncthreads();
        if (tid == 0) upart[b] = ps[0] + ps[1] + ps[2] + ps[3];
        __syncthreads();                           // protect ps before sqxs reuse
    }

    // ---- phase 0c: off-diag blocks wait for their two strips (acquire)
    if (b >= 32) {
        if (tid == 0) {
            while (atomicAdd(&flags[bi], 0u) != 1u) __builtin_amdgcn_s_sleep(8);
            while (atomicAdd(&flags[bj], 0u) != 1u) __builtin_amdgcn_s_sleep(8);
            __threadfence();                       // invalidate stale L1/L2
        }
        __syncthreads();
    }

    // ---- gram phase (R7 core, verbatim) ----
    const int wy = wave >> 1, wx = wave & 1;
    const int quad = lane >> 4, l15 = lane & 15;

    f32x4 acc[4][4];
    #pragma unroll
    for (int a = 0; a < 4; ++a)
        #pragma unroll
        for (int b2 = 0; b2 < 4; ++b2)
            acc[a][b2] = (f32x4){0.f, 0.f, 0.f, 0.f};

    const int c0  = wave * 2;
    const int rA  = lane >> 2;
    const int gsb = (((lane & 3) ^ ((lane >> 3) & 3))) * 16;

    const unsigned char* gA0 = Xf8 + (size_t)(i0 + c0 * 16 + rA) * KX8 + gsb;
    const unsigned char* gA1 = Xf8 + (size_t)(i0 + c0 * 16 + 16 + rA) * KX8 + gsb;
    const unsigned char* gB0 = Xf8 + (size_t)(j0 + c0 * 16 + rA) * KX8 + gsb;
    const unsigned char* gB1 = Xf8 + (size_t)(j0 + c0 * 16 + 16 + rA) * KX8 + gsb;

    if (tid < 128) {
        sqxs[tid] = sqx[i0 + tid]; sqxs[128 + tid] = sqx[j0 + tid];
        sqes[tid] = sqe[i0 + tid]; sqes[128 + tid] = sqe[j0 + tid];
    }
    __syncthreads();

    #pragma unroll
    for (int s = 0; s < 2; ++s) {
        gl2lds16(gA0, As + s * BUFB + c0 * 1024);
        gl2lds16(gA1, As + s * BUFB + c0 * 1024 + 1024);
        gl2lds16(gB0, Bs + s * BUFB + c0 * 1024);
        gl2lds16(gB1, Bs + s * BUFB + c0 * 1024 + 1024);
        gA0 += 64; gA1 += 64; gB0 += 64; gB1 += 64;
    }

    const int key = (l15 >> 1) & 3;
    const int boX = ((quad ^ key) << 4);

    int cur = 0;
    for (int t = 0; t < 13; ++t) {
        asm volatile("s_waitcnt vmcnt(4)" ::: "memory");
        __builtin_amdgcn_s_barrier();
        const int nb = (cur + 2 * BUFB >= 3 * BUFB) ? cur - BUFB : cur + 2 * BUFB;
        if (t < 11) {
            gl2lds16(gA0, As + nb + c0 * 1024);
            gl2lds16(gA1, As + nb + c0 * 1024 + 1024);
            gl2lds16(gB0, Bs + nb + c0 * 1024);
            gl2lds16(gB1, Bs + nb + c0 * 1024 + 1024);
            gA0 += 64; gA1 += 64; gB0 += 64; gB1 += 64;
        } else if (t == 11) {
            gl2lds16((const unsigned char*)(Ebf + (size_t)(i0 + c0 * 16 + rA) * 32) + gsb,
                     As + BUFB + c0 * 1024);
            gl2lds16((const unsigned char*)(Ebf + (size_t)(i0 + c0 * 16 + 16 + rA) * 32) + gsb,
                     As + BUFB + c0 * 1024 + 1024);
            gl2lds16((const unsigned char*)(Ebf + (size_t)(j0 + c0 * 16 + rA) * 32) + gsb,
                     Bs + BUFB + c0 * 1024);
            gl2lds16((const unsigned char*)(Ebf + (size_t)(j0 + c0 * 16 + 16 + rA) * 32) + gsb,
                     Bs + BUFB + c0 * 1024 + 1024);
        }
        long2v aF[4], bF[4];
        #pragma unroll
        for (int mi = 0; mi < 4; ++mi)
            aF[mi] = *(const long2v*)&As[cur + (wy * 64 + mi * 16 + l15) * 64 + boX];
        #pragma unroll
        for (int ni = 0; ni < 4; ++ni)
            bF[ni] = *(const long2v*)&Bs[cur + (wx * 64 + ni * 16 + l15) * 64 + boX];
        #pragma unroll
        for (int mi = 0; mi < 4; ++mi)
            #pragma unroll
            for (int ni = 0; ni < 4; ++ni) {
                acc[mi][ni] = __builtin_amdgcn_mfma_f32_16x16x32_fp8_fp8(
                    aF[mi][0], bF[ni][0], acc[mi][ni], 0, 0, 0);
                acc[mi][ni] = __builtin_amdgcn_mfma_f32_16x16x32_fp8_fp8(
                    aF[mi][1], bF[ni][1], acc[mi][ni], 0, 0, 0);
            }
        cur = (cur == 2 * BUFB) ? 0 : cur + BUFB;
    }
    asm volatile("s_waitcnt vmcnt(0)" ::: "memory");
    __builtin_amdgcn_s_barrier();

    // epilogue: E-gram streamed per mi + symmetric stats (R7 verbatim)
    const int slot_r = bj * 2 + wx;
    const int slot_c = bi * 2 + wy;
    bf16x8 bfrE[4];
    #pragma unroll
    for (int ni = 0; ni < 4; ++ni)
        bfrE[ni] = *(const bf16x8*)&Bs[BUFB + (wx * 64 + ni * 16 + l15) * 64 + boX];
    float cH[4] = {0,0,0,0}, cH2[4] = {0,0,0,0}, cL[4] = {0,0,0,0},
          cL2[4] = {0,0,0,0}, cHL[4] = {0,0,0,0};
    #pragma unroll
    for (int mi = 0; mi < 4; ++mi) {
        bf16x8 afE = *(const bf16x8*)&As[BUFB + (wy * 64 + mi * 16 + l15) * 64 + boX];
        f32x4 aE[4];
        #pragma unroll
        for (int ni = 0; ni < 4; ++ni) {
            f32x4 z = (f32x4){0.f, 0.f, 0.f, 0.f};
            aE[ni] = __builtin_amdgcn_mfma_f32_16x16x32_bf16(afE, bfrE[ni], z, 0, 0, 0);
        }
        const int ilocb = wy * 64 + mi * 16 + quad * 4;
        float sH[4] = {0,0,0,0}, sH2[4] = {0,0,0,0}, sL[4] = {0,0,0,0},
              sL2[4] = {0,0,0,0}, sHL[4] = {0,0,0,0};
        #pragma unroll
        for (int ni = 0; ni < 4; ++ni) {
            const int jloc = wx * 64 + ni * 16 + l15;
            const int j = j0 + jloc;
            const float sqxj = sqxs[128 + jloc];
            const float sqej = sqes[128 + jloc];
            #pragma unroll
            for (int r = 0; r < 4; ++r) {
                const int iloc = ilocb + r;
                const int i = i0 + iloc;
                float H, L;
                if (i == j) { H = 0.f; L = 0.f; }
                else {
                    float d2  = sqxs[iloc] + sqxj - 2.0f * acc[mi][ni][r];
                    H = sqrtf(fmaxf(d2, 0.f));
                    float d2e = sqes[iloc] + sqej - 2.0f * aE[ni][r];
                    L = sqrtf(fmaxf(d2e, 0.f));
                }
                sH[r] += H; sH2[r] += H * H; sL[r] += L; sL2[r] += L * L; sHL[r] += H * L;
                cH[ni] += H; cH2[ni] += H * H; cL[ni] += L; cL2[ni] += L * L; cHL[ni] += H * L;
            }
        }
        #pragma unroll
        for (int r = 0; r < 4; ++r) {
            float v0 = sH[r], v1 = sH2[r], v2 = sL[r], v3 = sL2[r], v4 = sHL[r];
            #pragma unroll
            for (int off2 = 1; off2 < 16; off2 <<= 1) {
                v0 += __shfl_xor(v0, off2, 64);
                v1 += __shfl_xor(v1, off2, 64);
                v2 += __shfl_xor(v2, off2, 64);
                v3 += __shfl_xor(v3, off2, 64);
                v4 += __shfl_xor(v4, off2, 64);
            }
            if (l15 == 0) {
                const int i = i0 + ilocb + r;
                float* base = statsp + (size_t)slot_r * NB + i;
                base[0 * SLAB] = v0;
                base[1 * SLAB] = v1;
                base[2 * SLAB] = v2;
                base[3 * SLAB] = v3;
                base[4 * SLAB] = v4;
            }
        }
    }
    if (bi != bj) {
        #pragma unroll
        for (int ni = 0; ni < 4; ++ni) {
            float v0 = cH[ni], v1 = cH2[ni], v2 = cL[ni], v3 = cL2[ni], v4 = cHL[ni];
            #pragma unroll
            for (int off2 = 16; off2 < 64; off2 <<= 1) {
                v0 += __shfl_xor(v0, off2, 64);
                v1 += __shfl_xor(v1, off2, 64);
                v2 += __shfl_xor(v2, off2, 64);
                v3 += __shfl_xor(v3, off2, 64);
                v4 += __shfl_xor(v4, off2, 64);
            }
            if (quad == 0) {
                const int j = j0 + wx * 64 + ni * 16 + l15;
                float* base = statsp + (size_t)slot_c * NB + j;
                base[0 * SLAB] = v0;
                base[1 * SLAB] = v1;
                base[2 * SLAB] = v2;
                base[3 * SLAB] = v3;
                base[4 * SLAB] = v4;
            }
        }
    }

    // ---- arrival (release stats) ----
    __syncthreads();
    if (tid == 0) { __threadfence(); atomicAdd(done_cnt, 1u); }

    // ---- finish phase: blocks 464..527 (64 finishers; spinners occupy <=64
    // of 768 resident slots, remaining blocks always schedulable) ----
    if (b >= NBLK - 64) {
        const int fb = b - (NBLK - 64);
        if (tid == 0) {
            while (atomicAdd(done_cnt, 0u) != (unsigned)NBLK) __builtin_amdgcn_s_sleep(8);
            __threadfence();                       // acquire all stats
        }
        __syncthreads();
        float (*ps2)[64][5] = (float (*)[64][5])smem;   // aliases dead As
        int* lastFlag = (int*)(smem + 10240);
        float* fin = (float*)(smem + 10256);
        const int rloc = tid & 63;
        const int sg = tid >> 6;
        const int r = fb * 64 + rloc;
        float sh = 0.f, sh2 = 0.f, sl = 0.f, sl2 = 0.f, shl = 0.f;
        for (int s = sg * 16; s < sg * 16 + 16; ++s) {
            const float* base = statsp + (size_t)s * NB + r;
            sh  += base[0 * SLAB];
            sh2 += base[1 * SLAB];
            sl  += base[2 * SLAB];
            sl2 += base[3 * SLAB];
            shl += base[4 * SLAB];
        }
        ps2[sg][rloc][0] = sh; ps2[sg][rloc][1] = sh2; ps2[sg][rloc][2] = sl;
        ps2[sg][rloc][3] = sl2; ps2[sg][rloc][4] = shl;
        __syncthreads();
        if (tid < 64) {
            float a = 0.f, b2 = 0.f, c = 0.f, d = 0.f, e = 0.f;
            #pragma unroll
            for (int g = 0; g < 4; ++g) {
                a += ps2[g][tid][0]; b2 += ps2[g][tid][1]; c += ps2[g][tid][2];
                d += ps2[g][tid][3]; e += ps2[g][tid][4];
            }
            const float invN = 1.0f / (float)NB;
            float num = e - a * c * invN;
            float vh  = fmaxf(b2 - a * a * invN, 0.f);
            float vl  = fmaxf(d - c * c * invN, 0.f);
            float local = num / (sqrtf(vh) * sqrtf(vl));
            #pragma unroll
            for (int off = 32; off; off >>= 1) local += __shfl_down(local, off, 64);
            if (tid == 0) cpart[fb] = local;
        }
        if (tid == 0) {
            __threadfence();
            unsigned prev = atomicAdd(fin_cnt, 1u);
            *lastFlag = (prev == 63u);
        }
        __syncthreads();
        if (*lastFlag) {
            __threadfence();
            float v = 0.f;
            if (tid < 64) v += cpart[tid] * (-BETA_C / (float)NB);
            if (tid < 96) v += upart[tid] * (ALPHA_C / (float)NTOT);
            #pragma unroll
            for (int off = 32; off; off >>= 1) v += __shfl_down(v, off, 64);
            if ((tid & 63) == 0) fin[tid >> 6] = v;
            __syncthreads();
            if (tid == 0) out[0] = fin[0] + fin[1] + fin[2] + fin[3];
        }
    }
}

extern "C" void kernel_launch(void* const* d_in, const int* in_sizes, int n_in,
                              void* d_out, int out_size, void* d_ws, size_t ws_size,
                              hipStream_t stream) {
    const float* emb  = (const float*)d_in[0];   // (4096, 32) f32
    const float* ph   = (const float*)d_in[1];   // (4096, 784) f32
    const int*   perm = (const int*)d_in[2];     // (20480,) i32
    float* out = (float*)d_out;

    char* ws = (char*)d_ws;
    unsigned char* Xf8 = (unsigned char*)(ws + WS_XF8);
    bf16*  Ebf     = (bf16*) (ws + WS_EBF);
    float* sqx     = (float*)(ws + WS_SQX);
    float* sqe     = (float*)(ws + WS_SQE);
    float* statsp  = (float*)(ws + WS_STATSP);
    float* upart   = (float*)(ws + WS_UPART);
    float* cpart   = (float*)(ws + WS_CPART);
    unsigned* flags    = (unsigned*)(ws + WS_FLAGS);
    unsigned* done_cnt = (unsigned*)(ws + WS_DONE);
    unsigned* fin_cnt  = (unsigned*)(ws + WS_FIN);

    mega_kernel<<<NBLK, 256, 0, stream>>>(ph, emb, perm, Xf8, Ebf, sqx, sqe,
                                          statsp, upart, cpart, flags,
                                          done_cnt, fin_cnt, out);
}

// Round 10
// 145.085 us; speedup vs baseline: 1.3210x; 1.3210x over previous
//
#include <hip/hip_runtime.h>
#include <hip/hip_bf16.h>
#include <math.h>

// Problem constants
#define NB    4096
#define DH    784
#define KX8   832            // fp8 row bytes: 784 padded to 13*64
#define NSR   5
#define NNEG  (NB*NSR)       // 20480
#define NTOT  (NB + NNEG)    // 24576

#define A_CONST 1.576943f
#define PEXP    1.7901216f   // 2*B_PARAM
#define EPS_C   1.0e-4f
#define ALPHA_C 0.9296875f   // BATCH_COUNT=500: beta=0.5*(1-500/800)^2=0.0703125
#define BETA_C  0.0703125f

#define NSLOT 64             // per row: 32 block-contribs x 2 wave-halves
#define SLAB  (NB * NSLOT)   // elements per stat component = 262144
#define NBLK  528            // upper-triangular 32x32 block grid (8*66)
#define BUFB  8192           // LDS buffer stride in BYTES (128 rows x 64 B)

typedef __hip_bfloat16 bf16;
typedef short bf16x8 __attribute__((ext_vector_type(8)));
typedef float f32x4  __attribute__((ext_vector_type(4)));
typedef long long2v __attribute__((ext_vector_type(2)));

// Workspace layout (bytes)
#define WS_XF8    0                      // 4096*832   = 3407872
#define WS_EBF    3407872                // 4096*32*2  = 262144
#define WS_SQX    3670016                // 4096*4     = 16384
#define WS_SQE    3686400                // 4096*4     = 16384
#define WS_STATSP 3702784                // 5*262144*4 = 5242880
#define WS_UPART  8945664                // 96*4       = 384
#define WS_CPART  8946048                // 64*4       = 256
#define WS_CNT    8946304                // 4

__device__ __forceinline__ void gl2lds16(const void* g, void* l) {
    __builtin_amdgcn_global_load_lds(
        (const __attribute__((address_space(1))) unsigned int*)g,
        (__attribute__((address_space(3))) unsigned int*)l,
        16, 0, 0);
}

// ---- fused prep: blocks 0..1023 -> X cast to fp8-e4m3, column-permuted layout
// (64B chunk c: dest dword p=4q+2h+w sources src dword c*16+h*8+q*2+w, so a
// lane's 16B at quad*16 = [K-half0 cols 8q..8q+7 | K-half1 cols 32+8q..+7]).
// Coalesced reads, permuted writes. blocks 1024..1119 -> UMAP CE + e_to prep.
__global__ void prep_fused(const float* __restrict__ X, const float* __restrict__ emb,
                           const int* __restrict__ perm, unsigned char* __restrict__ Xf8,
                           float* __restrict__ sqx, bf16* __restrict__ Ebf,
                           float* __restrict__ sqe, float* __restrict__ upart,
                           unsigned* __restrict__ cnt) {
    if (blockIdx.x == 0 && threadIdx.x == 0) *cnt = 0u;   // for finish1 last-block
    if (blockIdx.x < 1024) {
        const int wave = threadIdx.x >> 6, lane = threadIdx.x & 63;
        const int row = blockIdx.x * 4 + wave;
        const float4* xr = (const float4*)(X + (size_t)row * DH);
        int* xb = (int*)(Xf8 + (size_t)row * KX8);
        float s = 0.f;
        #pragma unroll
        for (int it = 0; it < 4; ++it) {
            const int src = lane + it * 64;     // src float4 index
            if (src < 208) {
                int pk = 0;
                if (src < 196) {
                    float4 v = xr[src];
                    s += v.x * v.x + v.y * v.y + v.z * v.z + v.w * v.w;
                    int lo = __builtin_amdgcn_cvt_pk_fp8_f32(v.x, v.y, 0, false);
                    pk = __builtin_amdgcn_cvt_pk_fp8_f32(v.z, v.w, lo, true);
                }
                const int c = src >> 4, sc = src & 15;
                const int h = sc >> 3, q = (sc >> 1) & 3, w = sc & 1;
                xb[c * 16 + q * 4 + h * 2 + w] = pk;
            }
        }
        #pragma unroll
        for (int off = 32; off; off >>= 1) s += __shfl_down(s, off, 64);
        if (lane == 0) sqx[row] = s;
        return;
    }
    // UMAP CE + e_to bf16 prep
    const int ub = blockIdx.x - 1024;
    const int t = ub * 256 + threadIdx.x;
    float val = 0.f;
    if (t < NB) {
        const float4* av = (const float4*)(emb + (size_t)t * 32);
        float4 t0 = av[0], t1 = av[1], t2 = av[2], t3 = av[3];   // e_to
        float4 f0 = av[4], f1 = av[5], f2 = av[6], f3 = av[7];   // e_from
        bf16* eb = Ebf + (size_t)t * 32;
        union { bf16 h[4]; ushort4 u; } cv;
        #define ST4(dst, q) cv.h[0]=__float2bfloat16(q.x); cv.h[1]=__float2bfloat16(q.y); \
                            cv.h[2]=__float2bfloat16(q.z); cv.h[3]=__float2bfloat16(q.w); \
                            *(ushort4*)(dst) = cv.u;
        ST4(eb,      t0) ST4(eb + 4,  t1) ST4(eb + 8,  t2) ST4(eb + 12, t3)
        #undef ST4
        ushort4 z = {0, 0, 0, 0};
        *(ushort4*)(eb + 16) = z; *(ushort4*)(eb + 20) = z;
        *(ushort4*)(eb + 24) = z; *(ushort4*)(eb + 28) = z;
        sqe[t] = t0.x*t0.x + t0.y*t0.y + t0.z*t0.z + t0.w*t0.w
               + t1.x*t1.x + t1.y*t1.y + t1.z*t1.z + t1.w*t1.w
               + t2.x*t2.x + t2.y*t2.y + t2.z*t2.z + t2.w*t2.w
               + t3.x*t3.x + t3.y*t3.y + t3.z*t3.z + t3.w*t3.w;
        float d2 = 0.f;
        #define D2(a, b) { float4 df = {a.x-b.x, a.y-b.y, a.z-b.z, a.w-b.w}; \
                           d2 += df.x*df.x + df.y*df.y + df.z*df.z + df.w*df.w; }
        D2(t0, f0) D2(t1, f1) D2(t2, f2) D2(t3, f3)
        #undef D2
        float d = sqrtf(d2);
        float p = 1.f / (1.f + A_CONST * powf(d, PEXP));
        val = -logf(fminf(fmaxf(p, EPS_C), 1.f));
    } else if (t < NTOT) {
        const int k = t - NB;
        const int ti = k / 5;
        const int fi = perm[k] / 5;
        const float4* at = (const float4*)(emb + (size_t)ti * 32);
        const float4* bt = (const float4*)(emb + (size_t)fi * 32 + 16);
        float d2 = 0.f;
        #pragma unroll
        for (int q = 0; q < 4; ++q) {
            float4 a = at[q], b = bt[q];
            float4 df = {a.x-b.x, a.y-b.y, a.z-b.z, a.w-b.w};
            d2 += df.x*df.x + df.y*df.y + df.z*df.z + df.w*df.w;
        }
        float d = sqrtf(d2);
        float p = 1.f / (1.f + A_CONST * powf(d, PEXP));
        val = -logf(fminf(fmaxf(1.f - p, EPS_C), 1.f));
    }
    #pragma unroll
    for (int off = 32; off; off >>= 1) val += __shfl_down(val, off, 64);
    __shared__ float ps[4];
    if ((threadIdx.x & 63) == 0) ps[threadIdx.x >> 6] = val;
    __syncthreads();
    if (threadIdx.x == 0) upart[ub] = ps[0] + ps[1] + ps[2] + ps[3];
}

// ---- main: upper-triangular 128x128 fp8 X-gram, double-buffered with the
// ISSUE-AFTER-READS pipeline: per stage [waitcnt(0); s_barrier; ds_read cur;
// issue DMA next; MFMA]. The explicit pre-barrier drain covers last stage's
// DMA (one full stage of head start); the compiler's conservative drain
// before ds_read becomes a no-op instead of killing a just-issued prefetch.
__global__ __launch_bounds__(256, 3) void gram_kernel(
    const unsigned char* __restrict__ Xf8, const bf16* __restrict__ Ebf,
    const float* __restrict__ sqx, const float* __restrict__ sqe,
    float* __restrict__ statsp) {
    __shared__ unsigned char As[2 * BUFB];   // 16 KB (double-buffered 128 x 64 B)
    __shared__ unsigned char Bs[2 * BUFB];   // 16 KB
    __shared__ float sqxs[256];              // [0..127]=i rows, [128..255]=j cols
    __shared__ float sqes[256];

    // XCD swizzle: 528 = 8*66; XCD k gets 66 consecutive triangle entries.
    int n = (blockIdx.x & 7) * 66 + (blockIdx.x >> 3);
    int bi = 0;
    while (n >= 32 - bi) { n -= 32 - bi; ++bi; }
    const int bj = bi + n;
    const int i0 = bi * 128, j0 = bj * 128;

    const int tid  = threadIdx.x;
    const int wave = tid >> 6;
    const int lane = tid & 63;
    const int wy = wave >> 1, wx = wave & 1;
    const int quad = lane >> 4, l15 = lane & 15;

    f32x4 acc[4][4];
    #pragma unroll
    for (int a = 0; a < 4; ++a)
        #pragma unroll
        for (int b = 0; b < 4; ++b)
            acc[a][b] = (f32x4){0.f, 0.f, 0.f, 0.f};

    // staging: 8 chunks of 16 rows; wave stages chunks {2w,2w+1}.
    // lane L: row chunk*16 + (L>>2); global 16-B seg (L&3)^((L>>3)&3).
    const int c0  = wave * 2;
    const int rA  = lane >> 2;
    const int gsb = (((lane & 3) ^ ((lane >> 3) & 3))) * 16;

    const unsigned char* gA0 = Xf8 + (size_t)(i0 + c0 * 16 + rA) * KX8 + gsb;
    const unsigned char* gA1 = Xf8 + (size_t)(i0 + c0 * 16 + 16 + rA) * KX8 + gsb;
    const unsigned char* gB0 = Xf8 + (size_t)(j0 + c0 * 16 + rA) * KX8 + gsb;
    const unsigned char* gB1 = Xf8 + (size_t)(j0 + c0 * 16 + 16 + rA) * KX8 + gsb;

    // sq-norms -> LDS, then full __syncthreads (no DMA in flight yet: free)
    if (tid < 128) {
        sqxs[tid] = sqx[i0 + tid]; sqxs[128 + tid] = sqx[j0 + tid];
        sqes[tid] = sqe[i0 + tid]; sqes[128 + tid] = sqe[j0 + tid];
    }
    __syncthreads();

    // prologue: prefetch stage 0 into buf 0
    gl2lds16(gA0, As + c0 * 1024);
    gl2lds16(gA1, As + c0 * 1024 + 1024);
    gl2lds16(gB0, Bs + c0 * 1024);
    gl2lds16(gB1, Bs + c0 * 1024 + 1024);
    gA0 += 64; gA1 += 64; gB0 += 64; gB1 += 64;

    // fragment byte offset: 16B = [h0 8B | h1 8B] for this lane's quad
    // (column-permuted layout), at swizzled position quad^key.
    const int key = (l15 >> 1) & 3;
    const int boX = ((quad ^ key) << 4);

    int cur = 0;
    for (int t = 0; t < 13; ++t) {
        // drain own last-stage DMA (it had a full stage in flight), then sync
        asm volatile("s_waitcnt vmcnt(0)" ::: "memory");
        __builtin_amdgcn_s_barrier();
        // read fragments of current buffer FIRST...
        long2v aF[4], bF[4];
        #pragma unroll
        for (int mi = 0; mi < 4; ++mi)
            aF[mi] = *(const long2v*)&As[cur + (wy * 64 + mi * 16 + l15) * 64 + boX];
        #pragma unroll
        for (int ni = 0; ni < 4; ++ni)
            bF[ni] = *(const long2v*)&Bs[cur + (wx * 64 + ni * 16 + l15) * 64 + boX];
        // ...THEN issue next stage's DMA into the other buffer (safe: that
        // buffer's reads by all waves retired before this stage's barrier)
        const int nb = cur ^ BUFB;
        if (t < 12) {
            gl2lds16(gA0, As + nb + c0 * 1024);
            gl2lds16(gA1, As + nb + c0 * 1024 + 1024);
            gl2lds16(gB0, Bs + nb + c0 * 1024);
            gl2lds16(gB1, Bs + nb + c0 * 1024 + 1024);
            gA0 += 64; gA1 += 64; gB0 += 64; gB1 += 64;
        } else {   // t == 12: prefetch E (64-B bf16 rows, same geometry)
            gl2lds16((const unsigned char*)(Ebf + (size_t)(i0 + c0 * 16 + rA) * 32) + gsb,
                     As + nb + c0 * 1024);
            gl2lds16((const unsigned char*)(Ebf + (size_t)(i0 + c0 * 16 + 16 + rA) * 32) + gsb,
                     As + nb + c0 * 1024 + 1024);
            gl2lds16((const unsigned char*)(Ebf + (size_t)(j0 + c0 * 16 + rA) * 32) + gsb,
                     Bs + nb + c0 * 1024);
            gl2lds16((const unsigned char*)(Ebf + (size_t)(j0 + c0 * 16 + 16 + rA) * 32) + gsb,
                     Bs + nb + c0 * 1024 + 1024);
        }
        #pragma unroll
        for (int mi = 0; mi < 4; ++mi)
            #pragma unroll
            for (int ni = 0; ni < 4; ++ni) {
                acc[mi][ni] = __builtin_amdgcn_mfma_f32_16x16x32_fp8_fp8(
                    aF[mi][0], bF[ni][0], acc[mi][ni], 0, 0, 0);
                acc[mi][ni] = __builtin_amdgcn_mfma_f32_16x16x32_fp8_fp8(
                    aF[mi][1], bF[ni][1], acc[mi][ni], 0, 0, 0);
            }
        cur ^= BUFB;
    }
    // E stage (buf cur): drain its DMA, sync all waves.
    asm volatile("s_waitcnt vmcnt(0)" ::: "memory");
    __builtin_amdgcn_s_barrier();

    // Epilogue. C/D layout: col = lane&15, row = quad*4 + reg  [m89/m91]
    // E-gram (bf16) streamed per mi; H^2 = max(d2,0), L^2 = max(d2e,0) (free).
    const int slot_r = bj * 2 + wx;
    const int slot_c = bi * 2 + wy;
    bf16x8 bfrE[4];
    #pragma unroll
    for (int ni = 0; ni < 4; ++ni)
        bfrE[ni] = *(const bf16x8*)&Bs[cur + (wx * 64 + ni * 16 + l15) * 64 + boX];
    float cH[4] = {0,0,0,0}, cH2[4] = {0,0,0,0}, cL[4] = {0,0,0,0},
          cL2[4] = {0,0,0,0}, cHL[4] = {0,0,0,0};
    #pragma unroll
    for (int mi = 0; mi < 4; ++mi) {
        bf16x8 afE = *(const bf16x8*)&As[cur + (wy * 64 + mi * 16 + l15) * 64 + boX];
        f32x4 aE[4];
        #pragma unroll
        for (int ni = 0; ni < 4; ++ni) {
            f32x4 z = (f32x4){0.f, 0.f, 0.f, 0.f};
            aE[ni] = __builtin_amdgcn_mfma_f32_16x16x32_bf16(afE, bfrE[ni], z, 0, 0, 0);
        }
        const int ilocb = wy * 64 + mi * 16 + quad * 4;
        float sH[4] = {0,0,0,0}, sH2[4] = {0,0,0,0}, sL[4] = {0,0,0,0},
              sL2[4] = {0,0,0,0}, sHL[4] = {0,0,0,0};
        #pragma unroll
        for (int ni = 0; ni < 4; ++ni) {
            const int jloc = wx * 64 + ni * 16 + l15;
            const int j = j0 + jloc;
            const float sqxj = sqxs[128 + jloc];
            const float sqej = sqes[128 + jloc];
            #pragma unroll
            for (int r = 0; r < 4; ++r) {
                const int iloc = ilocb + r;
                const int i = i0 + iloc;
                float H, L, H2, L2;
                if (i == j) { H = 0.f; L = 0.f; H2 = 0.f; L2 = 0.f; }
                else {
                    H2 = fmaxf(sqxs[iloc] + sqxj - 2.0f * acc[mi][ni][r], 0.f);
                    H = sqrtf(H2);
                    L2 = fmaxf(sqes[iloc] + sqej - 2.0f * aE[ni][r], 0.f);
                    L = sqrtf(L2);
                }
                sH[r] += H; sH2[r] += H2; sL[r] += L; sL2[r] += L2; sHL[r] += H * L;
                cH[ni] += H; cH2[ni] += H2; cL[ni] += L; cL2[ni] += L2; cHL[ni] += H * L;
            }
        }
        #pragma unroll
        for (int r = 0; r < 4; ++r) {
            float v0 = sH[r], v1 = sH2[r], v2 = sL[r], v3 = sL2[r], v4 = sHL[r];
            #pragma unroll
            for (int off2 = 1; off2 < 16; off2 <<= 1) {   // reduce over l15
                v0 += __shfl_xor(v0, off2, 64);
                v1 += __shfl_xor(v1, off2, 64);
                v2 += __shfl_xor(v2, off2, 64);
                v3 += __shfl_xor(v3, off2, 64);
                v4 += __shfl_xor(v4, off2, 64);
            }
            if (l15 == 0) {
                const int i = i0 + ilocb + r;
                float* base = statsp + (size_t)slot_r * NB + i;   // [c][slot][i]
                base[0 * SLAB] = v0;
                base[1 * SLAB] = v1;
                base[2 * SLAB] = v2;
                base[3 * SLAB] = v3;
                base[4 * SLAB] = v4;
            }
        }
    }
    if (bi != bj) {
        #pragma unroll
        for (int ni = 0; ni < 4; ++ni) {
            float v0 = cH[ni], v1 = cH2[ni], v2 = cL[ni], v3 = cL2[ni], v4 = cHL[ni];
            #pragma unroll
            for (int off2 = 16; off2 < 64; off2 <<= 1) {   // reduce over quad
                v0 += __shfl_xor(v0, off2, 64);
                v1 += __shfl_xor(v1, off2, 64);
                v2 += __shfl_xor(v2, off2, 64);
                v3 += __shfl_xor(v3, off2, 64);
                v4 += __shfl_xor(v4, off2, 64);
            }
            if (quad == 0) {
                const int j = j0 + wx * 64 + ni * 16 + l15;
                float* base = statsp + (size_t)slot_c * NB + j;
                base[0 * SLAB] = v0;
                base[1 * SLAB] = v1;
                base[2 * SLAB] = v2;
                base[3 * SLAB] = v3;
                base[4 * SLAB] = v4;
            }
        }
    }
}

// ---- finish1: reduce 64 slots per row, per-row corr; last block folds partials -> out
__global__ void finish1_kernel(const float* __restrict__ statsp, const float* __restrict__ upart,
                               float* __restrict__ cpart, unsigned* __restrict__ cnt,
                               float* __restrict__ out) {
    __shared__ float ps2[4][64][5];
    const int t = threadIdx.x;
    const int rloc = t & 63;
    const int sg = t >> 6;
    const int r = blockIdx.x * 64 + rloc;
    float sh = 0.f, sh2 = 0.f, sl = 0.f, sl2 = 0.f, shl = 0.f;
    for (int s = sg * 16; s < sg * 16 + 16; ++s) {
        const float* base = statsp + (size_t)s * NB + r;
        sh  += base[0 * SLAB];
        sh2 += base[1 * SLAB];
        sl  += base[2 * SLAB];
        sl2 += base[3 * SLAB];
        shl += base[4 * SLAB];
    }
    ps2[sg][rloc][0] = sh; ps2[sg][rloc][1] = sh2; ps2[sg][rloc][2] = sl;
    ps2[sg][rloc][3] = sl2; ps2[sg][rloc][4] = shl;
    __syncthreads();
    if (t < 64) {
        float a = 0.f, b = 0.f, c = 0.f, d = 0.f, e = 0.f;
        #pragma unroll
        for (int g = 0; g < 4; ++g) {
            a += ps2[g][t][0]; b += ps2[g][t][1]; c += ps2[g][t][2];
            d += ps2[g][t][3]; e += ps2[g][t][4];
        }
        const float invN = 1.0f / (float)NB;
        float num = e - a * c * invN;
        float vh  = fmaxf(b - a * a * invN, 0.f);
        float vl  = fmaxf(d - c * c * invN, 0.f);
        float local = num / (sqrtf(vh) * sqrtf(vl));
        #pragma unroll
        for (int off = 32; off; off >>= 1) local += __shfl_down(local, off, 64);
        if (t == 0) cpart[blockIdx.x] = local;
    }
    // last block folds 64 corr partials + 96 umap partials into the loss
    __shared__ int lastFlag;
    if (t == 0) {
        __threadfence();                       // cpart store visible device-wide
        unsigned prev = atomicAdd(cnt, 1u);
        lastFlag = (prev == 63u);
    }
    __syncthreads();
    if (lastFlag) {
        __threadfence();                       // acquire other blocks' cpart
        float v = 0.f;
        if (t < 64) v += cpart[t] * (-BETA_C / (float)NB);
        if (t < 96) v += upart[t] * (ALPHA_C / (float)NTOT);
        #pragma unroll
        for (int off = 32; off; off >>= 1) v += __shfl_down(v, off, 64);
        __shared__ float fin[4];
        if ((t & 63) == 0) fin[t >> 6] = v;
        __syncthreads();
        if (t == 0) out[0] = fin[0] + fin[1] + fin[2] + fin[3];
    }
}

extern "C" void kernel_launch(void* const* d_in, const int* in_sizes, int n_in,
                              void* d_out, int out_size, void* d_ws, size_t ws_size,
                              hipStream_t stream) {
    const float* emb  = (const float*)d_in[0];   // (4096, 32) f32
    const float* ph   = (const float*)d_in[1];   // (4096, 784) f32
    const int*   perm = (const int*)d_in[2];     // (20480,) i32
    float* out = (float*)d_out;

    char* ws = (char*)d_ws;
    unsigned char* Xf8 = (unsigned char*)(ws + WS_XF8);
    bf16*  Ebf    = (bf16*) (ws + WS_EBF);
    float* sqx    = (float*)(ws + WS_SQX);
    float* sqe    = (float*)(ws + WS_SQE);
    float* statsp = (float*)(ws + WS_STATSP);
    float* upart  = (float*)(ws + WS_UPART);
    float* cpart  = (float*)(ws + WS_CPART);
    unsigned* cnt = (unsigned*)(ws + WS_CNT);

    prep_fused<<<1120, 256, 0, stream>>>(ph, emb, perm, Xf8, sqx, Ebf, sqe, upart, cnt);
    gram_kernel<<<NBLK, 256, 0, stream>>>(Xf8, Ebf, sqx, sqe, statsp);
    finish1_kernel<<<64, 256, 0, stream>>>(statsp, upart, cpart, cnt, out);
}